// Round 3
// baseline (803.664 us; speedup 1.0000x reference)
//
#include <hip/hip_runtime.h>
#include <hip/hip_bf16.h>
#include <stdint.h>
#include <math.h>

#define NTOK  2048
#define HDIM  1024
#define FDIM  768
#define NEXP  32
#define TOPK  8
#define CAP   1024
#define LDP   72      // padded LDS row stride (shorts): 144B = 9*16B, rows alias 2-way (free)

typedef __attribute__((ext_vector_type(8))) short short8;
typedef __attribute__((ext_vector_type(4))) float f32x4;

__device__ __forceinline__ short f2bf(float f) {
  union { float f; uint32_t u; } c; c.f = f;
  uint32_t u = c.u;
  u += 0x7fffu + ((u >> 16) & 1u);   // RNE
  return (short)(u >> 16);
}

__device__ __forceinline__ short8 pack8(float4 a, float4 b) {
  short8 r;
  r[0] = f2bf(a.x); r[1] = f2bf(a.y); r[2] = f2bf(a.z); r[3] = f2bf(a.w);
  r[4] = f2bf(b.x); r[5] = f2bf(b.y); r[6] = f2bf(b.z); r[7] = f2bf(b.w);
  return r;
}

// packed fp32->bf16 (round-half-up): dst = bf(a) | bf(b)<<16
__device__ __forceinline__ uint32_t pkbf(float a, float b) {
  return __builtin_amdgcn_perm(__float_as_uint(b) + 0x8000u,
                               __float_as_uint(a) + 0x8000u, 0x07060302u);
}

__device__ __forceinline__ uint4 pack8u(float4 a, float4 b) {
  uint4 r;
  r.x = pkbf(a.x, a.y);
  r.y = pkbf(a.z, a.w);
  r.z = pkbf(b.x, b.y);
  r.w = pkbf(b.z, b.w);
  return r;
}

// ---------------- router: fp32 logits, top-8, renorm weights, scatter, x->bf16 ----------------
__global__ __launch_bounds__(256) void router_kern(
    const float* __restrict__ x, const float* __restrict__ gw,
    int* __restrict__ cnt, int* __restrict__ slot_tok,
    float* __restrict__ slot_w, short* __restrict__ xb) {
  const int n0 = blockIdx.x * 4;      // 4 tokens per block, grid = 512
  const int t  = threadIdx.x;
  __shared__ float ls[4][32];

  const int e = t >> 3;               // expert
  const int j = t & 7;                // k-chunk residue
  float acc[4] = {0.f, 0.f, 0.f, 0.f};
  const float4* gw4 = (const float4*)(gw + (size_t)e * HDIM);
  const float4* x4  = (const float4*)(x + (size_t)n0 * HDIM);
  for (int i = 0; i < 32; ++i) {
    const int c = j + 8 * i;          // float4 chunk 0..255
    const float4 g = gw4[c];
#pragma unroll
    for (int tok = 0; tok < 4; ++tok) {
      const float4 xv = x4[tok * 256 + c];
      acc[tok] += g.x * xv.x + g.y * xv.y + g.z * xv.z + g.w * xv.w;
    }
  }
#pragma unroll
  for (int tok = 0; tok < 4; ++tok) {
    float v = acc[tok];
    v += __shfl_xor(v, 1); v += __shfl_xor(v, 2); v += __shfl_xor(v, 4);
    if (j == 0) ls[tok][e] = v;
  }
  __syncthreads();

  if (t < 4) {
    const int n = n0 + t;
    float lv[32];
#pragma unroll
    for (int i = 0; i < 32; ++i) lv[i] = ls[t][i];
    int   idx[TOPK];
    float val[TOPK];
    for (int kk = 0; kk < TOPK; ++kk) {
      float best = -INFINITY; int bi = 0;
      for (int i = 0; i < 32; ++i)
        if (lv[i] > best) { best = lv[i]; bi = i; }   // strict >: first-index tie-break
      val[kk] = best; idx[kk] = bi; lv[bi] = -INFINITY;
    }
    const float m = val[0];
    float w[TOPK]; float wsum = 0.f;
    for (int kk = 0; kk < TOPK; ++kk) { w[kk] = __expf(val[kk] - m); wsum += w[kk]; }
    const float inv = 1.f / wsum;
    for (int kk = 0; kk < TOPK; ++kk) {
      const int ee = idx[kk];
      const int pos = atomicAdd(&cnt[ee], 1);
      if (pos < CAP) {
        slot_tok[ee * CAP + pos] = n * TOPK + kk;
        slot_w[ee * CAP + pos]   = w[kk] * inv;
      }
    }
  }

  // x -> bf16 (RNE), 16 elems/thread
  const size_t base = (size_t)n0 * HDIM + (size_t)t * 16;
  const float4* xp = (const float4*)(x + base);
  short8* xo = (short8*)(xb + base);
  xo[0] = pack8(xp[0], xp[1]);
  xo[1] = pack8(xp[2], xp[3]);
}

// ---------------- GEMM1: h = silu(x@Wg^T) * (x@Wu^T) ----------------
// 128 token-rows x 64 f-cols (gate+up = 128 B-rows), BK=64, explicit VGPR staging
__global__ __launch_bounds__(256) void gemm1_kern(
    const short* __restrict__ xb, const float* __restrict__ gup,
    const int* __restrict__ cnt, const int* __restrict__ slot_tok,
    short* __restrict__ hbuf) {
  const int e = blockIdx.z;
  const int mcnt = min(cnt[e], CAP);
  const int r0 = blockIdx.y * 128;
  if (r0 >= mcnt) return;
  const int f0 = blockIdx.x * 64;

  __shared__ short As[128 * LDP];  // 18KB bf16 tokens
  __shared__ short Bs[128 * LDP];  // 18KB bf16 weights (rows: g0..31,u0..31,g32..63,u32..63)
  __shared__ int tokL[128];

  const int t = threadIdx.x;
  if (t < 128) {
    int s = (r0 + t < mcnt) ? slot_tok[e * CAP + r0 + t] : 0;
    tokL[t] = s >> 3;
  }
  __syncthreads();

  // staging: 2 threads per row, each covers 32 k-elements
  const int sr = t >> 1;            // row 0..127
  const int sk = (t & 1) * 32;      // k offset (elements)
  const short* aptr = xb + (size_t)tokL[sr] * HDIM + sk;
  const int frow = ((sr & 32) ? FDIM : 0) + f0 + ((sr >> 6) << 5) + (sr & 31);
  const float* bptr = gup + ((size_t)e * (2 * FDIM) + frow) * HDIM + sk;
  short* adst = &As[sr * LDP + sk];
  short* bdst = &Bs[sr * LDP + sk];

  const int wave = t >> 6, lane = t & 63;
  const int wm = wave & 1, wn = wave >> 1;
  const int lrow = lane & 15, q8 = (lane >> 4) * 8;

  f32x4 accg[4][2], accu[4][2];
#pragma unroll
  for (int a = 0; a < 4; ++a)
#pragma unroll
    for (int b = 0; b < 2; ++b) {
      accg[a][b] = (f32x4){0.f, 0.f, 0.f, 0.f};
      accu[a][b] = (f32x4){0.f, 0.f, 0.f, 0.f};
    }

  uint4 aR[4]; float4 bR[8];
#pragma unroll
  for (int i = 0; i < 4; ++i) aR[i] = *(const uint4*)(aptr + 8 * i);
#pragma unroll
  for (int i = 0; i < 8; ++i) bR[i] = *(const float4*)(bptr + 4 * i);

  for (int kb = 0; kb < HDIM; kb += 64) {
    __syncthreads();   // previous tile's LDS reads complete
#pragma unroll
    for (int i = 0; i < 4; ++i) *(uint4*)(adst + 8 * i) = aR[i];
#pragma unroll
    for (int i = 0; i < 4; ++i) *(uint4*)(bdst + 8 * i) = pack8u(bR[2 * i], bR[2 * i + 1]);
    __syncthreads();

    if (kb + 64 < HDIM) {           // prefetch next slab; latency hides under MFMA
#pragma unroll
      for (int i = 0; i < 4; ++i) aR[i] = *(const uint4*)(aptr + kb + 64 + 8 * i);
#pragma unroll
      for (int i = 0; i < 8; ++i) bR[i] = *(const float4*)(bptr + kb + 64 + 4 * i);
    }

#pragma unroll
    for (int ks = 0; ks < 64; ks += 32) {
      short8 af[4], bg[2], bu[2];
#pragma unroll
      for (int mt = 0; mt < 4; ++mt)
        af[mt] = *(const short8*)&As[(64 * wm + 16 * mt + lrow) * LDP + ks + q8];
#pragma unroll
      for (int nt = 0; nt < 2; ++nt) {
        bg[nt] = *(const short8*)&Bs[(64 * wn + 16 * nt + lrow) * LDP + ks + q8];
        bu[nt] = *(const short8*)&Bs[(64 * wn + 32 + 16 * nt + lrow) * LDP + ks + q8];
      }
#pragma unroll
      for (int mt = 0; mt < 4; ++mt)
#pragma unroll
        for (int nt = 0; nt < 2; ++nt) {
          accg[mt][nt] = __builtin_amdgcn_mfma_f32_16x16x32_bf16(af[mt], bg[nt], accg[mt][nt], 0, 0, 0);
          accu[mt][nt] = __builtin_amdgcn_mfma_f32_16x16x32_bf16(af[mt], bu[nt], accu[mt][nt], 0, 0, 0);
        }
    }
  }

  // epilogue: silu(g)*u -> bf16 hbuf[e][pos][f]
#pragma unroll
  for (int mt = 0; mt < 4; ++mt)
#pragma unroll
    for (int nt = 0; nt < 2; ++nt)
#pragma unroll
      for (int r = 0; r < 4; ++r) {
        const int pos = r0 + 64 * wm + 16 * mt + (lane >> 4) * 4 + r;
        if (pos < mcnt) {
          const int f = f0 + 32 * wn + 16 * nt + lrow;
          const float g = accg[mt][nt][r];
          const float u = accu[mt][nt][r];
          const float hv = (g / (1.f + __expf(-g))) * u;
          hbuf[((size_t)e * CAP + pos) * FDIM + f] = f2bf(hv);
        }
      }
}

// ---------------- GEMM2: slot_out[s] = w_s * (h @ Wd^T) ----------------
// 128 rows x 128 H-cols, BK=64, explicit VGPR staging
__global__ __launch_bounds__(256) void gemm2_kern(
    const short* __restrict__ hbuf, const float* __restrict__ dwn,
    const int* __restrict__ cnt, const int* __restrict__ slot_tok,
    const float* __restrict__ slot_w, float* __restrict__ slot_out) {
  const int e = blockIdx.z;
  const int mcnt = min(cnt[e], CAP);
  const int r0 = blockIdx.y * 128;
  if (r0 >= mcnt) return;
  const int n0 = blockIdx.x * 128;

  __shared__ short As[128 * LDP];
  __shared__ short Bs[128 * LDP];
  __shared__ int   tokL[128];
  __shared__ float wL[128];

  const int t = threadIdx.x;
  if (t < 128) {
    const bool v = (r0 + t) < mcnt;
    tokL[t] = v ? slot_tok[e * CAP + r0 + t] : 0;
    wL[t]   = v ? slot_w[e * CAP + r0 + t] : 0.f;
  }
  __syncthreads();

  const int sr = t >> 1;
  const int sk = (t & 1) * 32;
  const short* aptr = hbuf + ((size_t)e * CAP + r0 + sr) * FDIM + sk;
  const float* bptr = dwn + ((size_t)e * HDIM + n0 + sr) * FDIM + sk;
  short* adst = &As[sr * LDP + sk];
  short* bdst = &Bs[sr * LDP + sk];

  const int wave = t >> 6, lane = t & 63;
  const int wm = wave & 1, wn = wave >> 1;
  const int lrow = lane & 15, q8 = (lane >> 4) * 8;

  f32x4 acc[4][4];
#pragma unroll
  for (int a = 0; a < 4; ++a)
#pragma unroll
    for (int b = 0; b < 4; ++b) acc[a][b] = (f32x4){0.f, 0.f, 0.f, 0.f};

  uint4 aR[4]; float4 bR[8];
#pragma unroll
  for (int i = 0; i < 4; ++i) aR[i] = *(const uint4*)(aptr + 8 * i);
#pragma unroll
  for (int i = 0; i < 8; ++i) bR[i] = *(const float4*)(bptr + 4 * i);

  for (int kb = 0; kb < FDIM; kb += 64) {
    __syncthreads();
#pragma unroll
    for (int i = 0; i < 4; ++i) *(uint4*)(adst + 8 * i) = aR[i];
#pragma unroll
    for (int i = 0; i < 4; ++i) *(uint4*)(bdst + 8 * i) = pack8u(bR[2 * i], bR[2 * i + 1]);
    __syncthreads();

    if (kb + 64 < FDIM) {
#pragma unroll
      for (int i = 0; i < 4; ++i) aR[i] = *(const uint4*)(aptr + kb + 64 + 8 * i);
#pragma unroll
      for (int i = 0; i < 8; ++i) bR[i] = *(const float4*)(bptr + kb + 64 + 4 * i);
    }

#pragma unroll
    for (int ks = 0; ks < 64; ks += 32) {
      short8 af[4], bf[4];
#pragma unroll
      for (int mt = 0; mt < 4; ++mt)
        af[mt] = *(const short8*)&As[(64 * wm + 16 * mt + lrow) * LDP + ks + q8];
#pragma unroll
      for (int nt = 0; nt < 4; ++nt)
        bf[nt] = *(const short8*)&Bs[(64 * wn + 16 * nt + lrow) * LDP + ks + q8];
#pragma unroll
      for (int mt = 0; mt < 4; ++mt)
#pragma unroll
        for (int nt = 0; nt < 4; ++nt)
          acc[mt][nt] = __builtin_amdgcn_mfma_f32_16x16x32_bf16(af[mt], bf[nt], acc[mt][nt], 0, 0, 0);
    }
  }

#pragma unroll
  for (int mt = 0; mt < 4; ++mt)
#pragma unroll
    for (int nt = 0; nt < 4; ++nt)
#pragma unroll
      for (int r = 0; r < 4; ++r) {
        const int prow = 64 * wm + 16 * mt + (lane >> 4) * 4 + r;
        if (r0 + prow < mcnt) {
          const int s = tokL[prow];
          const float w = wL[prow];
          const int col = n0 + 64 * wn + 16 * nt + lrow;
          slot_out[(size_t)s * HDIM + col] = w * acc[mt][nt][r];
        }
      }
}

// ---------------- gather: out[n] = sum_k slot_out[n*8+k] ----------------
__global__ __launch_bounds__(256) void gather_kern(
    const float* __restrict__ so, float* __restrict__ out) {
  const int n = blockIdx.x;
  const int c = threadIdx.x * 4;
  float4 a = make_float4(0.f, 0.f, 0.f, 0.f);
#pragma unroll
  for (int k = 0; k < TOPK; ++k) {
    const float4 v = *(const float4*)&so[((size_t)(n * TOPK + k)) * HDIM + c];
    a.x += v.x; a.y += v.y; a.z += v.z; a.w += v.w;
  }
  *(float4*)&out[(size_t)n * HDIM + c] = a;
}

extern "C" void kernel_launch(void* const* d_in, const int* in_sizes, int n_in,
                              void* d_out, int out_size, void* d_ws, size_t ws_size,
                              hipStream_t stream) {
  const float* x   = (const float*)d_in[0];
  const float* gw  = (const float*)d_in[1];
  const float* gup = (const float*)d_in[2];
  const float* dwn = (const float*)d_in[3];
  float* out = (float*)d_out;

  char* ws = (char*)d_ws;
  // layout: cnt(1KB) | slot_tok(128KB) | slot_w(128KB) | pad | xb(4MB) | h(48MB) | slot_out(64MB)
  int*   cnt      = (int*)(ws + 0);
  int*   slot_tok = (int*)(ws + 1024);
  float* slot_w   = (float*)(ws + 1024 + 131072);
  short* xb       = (short*)(ws + 524288);
  short* hbuf     = (short*)(ws + 524288 + 4194304);
  float* slot_out = (float*)(ws + 524288 + 4194304 + 50331648);

  hipMemsetAsync(cnt, 0, 1024, stream);
  router_kern<<<NTOK / 4, 256, 0, stream>>>(x, gw, cnt, slot_tok, slot_w, xb);
  gemm1_kern<<<dim3(FDIM / 64, CAP / 128, NEXP), 256, 0, stream>>>(xb, gup, cnt, slot_tok, hbuf);
  gemm2_kern<<<dim3(HDIM / 128, CAP / 128, NEXP), 256, 0, stream>>>(hbuf, dwn, cnt, slot_tok, slot_w, slot_out);
  gather_kern<<<NTOK, 256, 0, stream>>>(slot_out, out);
}